// Round 19
// baseline (855.774 us; speedup 1.0000x reference)
//
#include <hip/hip_runtime.h>
#include <hip/hip_bf16.h>
#include <hip/hip_cooperative_groups.h>

namespace cg = cooperative_groups;

#define BB 16
#define CC 512
#define HWP 4096
#define DD 256
#define NPIX 65536
#define INV_SQRT_C 0.04419417382415922f

typedef unsigned short u16;
typedef __attribute__((ext_vector_type(8))) short s16x8;
typedef __attribute__((ext_vector_type(8))) unsigned short u16x8;
typedef __attribute__((ext_vector_type(4))) unsigned short u16x4;
typedef __attribute__((ext_vector_type(4))) float f32x4;

__device__ __forceinline__ u16 f2b(float f){
  unsigned int u = __builtin_bit_cast(unsigned int, f);
  unsigned int r = (u + 0x7fffu + ((u >> 16) & 1u)) >> 16;
  return (u16)r;
}

__device__ __forceinline__ f32x4 mfma16(s16x8 a, s16x8 b, f32x4 c){
  return __builtin_amdgcn_mfma_f32_16x16x32_bf16(a, b, c, 0, 0, 0);
}

// S = sum_b X_b X_b^T via MFMA bf16. 128x128 tiles, upper tile-pairs (10),
// K-step 64 + split-K. Diagonal tiles ALSO accumulate xbar (channel sums).
__global__ __launch_bounds__(512) void k_gram(const float* __restrict__ x, float* __restrict__ Spart,
                                              float* __restrict__ xbar, int kspl){
  __shared__ __align__(16) u16 Asl[128*72];
  __shared__ __align__(16) u16 Bsl[128*72];
  int tid = threadIdx.x;
  int w = tid >> 6, lane = tid & 63, lr = lane & 15, g = lane >> 4;
  int b = blockIdx.y;
  int kz = blockIdx.z;
  int t = blockIdx.x, ti = 0, rem = 4;
  while (t >= rem){ t -= rem; ++ti; --rem; }
  int tj = ti + t;
  int r0 = ti*128, c0 = tj*128;
  bool isdiag = (ti == tj);
  int wm = w >> 2, wn = w & 3;
  f32x4 acc[4][2] = {};
  float xsum[8] = {};
  const float* xb = x + (size_t)b*CC*HWP;
  int klen = HWP / kspl;
  int kbase = kz * klen;
  for (int k0 = kbase; k0 < kbase + klen; k0 += 64){
    __syncthreads();
    #pragma unroll
    for (int s = 0; s < 8; ++s){
      int tt = tid + s*512;
      int arr = tt >> 11;
      int row = (tt >> 4) & 127;
      int q = tt & 15;
      const float* src = xb + (size_t)((arr ? c0 : r0) + row)*HWP + k0 + q*4;
      f32x4 v = *(const f32x4*)src;
      if (isdiag && arr == 0) xsum[s] += (v[0]+v[1]) + (v[2]+v[3]);
      u16x4 u; u[0]=f2b(v[0]); u[1]=f2b(v[1]); u[2]=f2b(v[2]); u[3]=f2b(v[3]);
      u16* dst = (arr ? Bsl : Asl) + row*72 + q*4;
      *(u16x4*)dst = u;
    }
    __syncthreads();
    #pragma unroll
    for (int kc = 0; kc < 2; ++kc){
      s16x8 av[4], bv[2];
      #pragma unroll
      for (int mt = 0; mt < 4; ++mt) av[mt] = *(const s16x8*)&Asl[(wm*64 + mt*16 + lr)*72 + kc*32 + g*8];
      #pragma unroll
      for (int nt = 0; nt < 2; ++nt) bv[nt] = *(const s16x8*)&Bsl[(wn*32 + nt*16 + lr)*72 + kc*32 + g*8];
      #pragma unroll
      for (int mt = 0; mt < 4; ++mt)
        #pragma unroll
        for (int nt = 0; nt < 2; ++nt)
          acc[mt][nt] = mfma16(av[mt], bv[nt], acc[mt][nt]);
    }
  }
  float* sp = Spart + (size_t)(b*kspl + kz)*262144;
  #pragma unroll
  for (int mt = 0; mt < 4; ++mt)
    #pragma unroll
    for (int nt = 0; nt < 2; ++nt)
      #pragma unroll
      for (int r = 0; r < 4; ++r)
        sp[(size_t)(r0 + wm*64 + mt*16 + 4*g + r)*512 + c0 + wn*32 + nt*16 + lr] = acc[mt][nt][r];

  if (isdiag){
    __syncthreads();
    float* scr = (float*)Asl;
    #pragma unroll
    for (int s = 0; s < 8; ++s){
      int tt = tid + s*512;
      if ((tt >> 11) == 0){
        int row = (tt >> 4) & 127, q = tt & 15;
        scr[row*16 + q] = xsum[s];
      }
    }
    __syncthreads();
    if (tid < 128){
      float rs = 0.f;
      #pragma unroll
      for (int j = 0; j < 16; ++j) rs += scr[tid*16 + j];
      atomicAdd(&xbar[r0 + tid], rs * (1.0f/(float)NPIX));
    }
  }
}

// merged: blocks 0..1023 = sreduce (slot sum + mirror); blocks 1024..1279 = G rows
__global__ __launch_bounds__(256) void k_sredG(const float* __restrict__ Spart, float* __restrict__ S,
                                               int nslots, const float* __restrict__ wg, float* __restrict__ G){
  if (blockIdx.x < 1024){
    int idx = blockIdx.x*256 + threadIdx.x;
    int i = idx >> 9, j = idx & 511;
    int src = ((i >> 7) <= (j >> 7)) ? idx : (j*512 + i);
    float s = 0.f;
    for (int k = 0; k < nslots; ++k) s += Spart[(size_t)k*262144 + src];
    S[idx] = s;
  } else {
    int i = blockIdx.x - 1024, j = threadIdx.x;
    float s = 0.f;
    for (int c = 0; c < CC; ++c)
      s = fmaf(wg[c*DD + i] + 1e-8f, wg[c*DD + j] + 1e-8f, s);
    G[i*DD + j] = s;
  }
}

// Cooperative QR: 8 Cholesky panel steps (grid.sync between) + row-parallel TRSM,
// all in ONE launch. grid = 8 blocks x 256 threads, 120KB LDS, co-resident.
__global__ __launch_bounds__(256) void k_qr(float* __restrict__ G, float* __restrict__ U,
    const float* __restrict__ wg,
    float* __restrict__ Q, float* __restrict__ Qst,
    u16* __restrict__ Qb, u16* __restrict__ Qstb){
  cg::grid_group grid = cg::this_grid();
  __shared__ __align__(16) float Pp[8192];     // 32KB; chol aliases Ur/Uc here
  __shared__ float Qlds[256*64];               // 64KB
  __shared__ float Wred[3*32*64];              // 24KB
  int tid = threadIdx.x;
  int lane = tid & 63;

  // ---- Phase A: blocked Cholesky, 8 steps with grid-wide sync ----
  for (int kb = 0; kb < 8; ++kb){
    int K0 = kb*32;
    int nt = 256 - K0 - 32;
    int T = (nt + 63) >> 6;
    int nblk = (nt > 0) ? T*(T+1)/2 : 1;
    if ((int)blockIdx.x < nblk){
      int j = lane & 31;
      int t = blockIdx.x, ti = 0, rem = T;
      if (nt > 0){ while (t >= rem){ t -= rem; ++ti; --rem; } }
      int tj = ti + t;
      int r0 = K0 + 32 + ti*64;
      int c0 = K0 + 32 + tj*64;
      float* Ur = Pp;            // [32][64]
      float* Uc = Pp + 2048;     // [32][64]

      // (a) diag factor in registers (redundant per wave)
      float c[32];
      #pragma unroll
      for (int i = 0; i < 32; ++i)
        c[i] = (i <= j) ? G[(K0+i)*DD + K0 + j] : 0.f;
      #pragma unroll
      for (int k = 0; k < 32; ++k){
        float piv = __shfl(c[k], k);
        float sd = sqrtf(piv);
        float ukj = c[k] / sd;
        c[k] = ukj;
        float uk[32];
        #pragma unroll
        for (int i = k + 1; i < 32; ++i) uk[i] = __shfl(ukj, i);
        #pragma unroll
        for (int i = k + 1; i < 32; ++i) c[i] -= uk[i] * ukj;
      }
      if (blockIdx.x == 0 && tid < 32){
        #pragma unroll
        for (int i = 0; i < 32; ++i)
          if (i <= j) U[(K0+i)*DD + K0 + j] = c[i];
      }

      if (nt > 0){
        // (b) panel solve for this tile's r/c column ranges; D via register shfl
        if (tid < 128){
          int half = tid >> 6;
          int cc = tid & 63;
          int gc = (half ? c0 : r0) + cc;
          bool act = gc < 256;
          float y[32];
          #pragma unroll
          for (int i = 0; i < 32; ++i) y[i] = act ? G[(K0+i)*DD + gc] : 0.f;
          #pragma unroll
          for (int i = 0; i < 32; ++i){
            float s0 = y[i];
            #pragma unroll
            for (int l = 0; l < 32; ++l)
              if (l < i) s0 -= __shfl(c[l], i) * y[l];
            y[i] = s0 / __shfl(c[i], i);
          }
          if (act){
            #pragma unroll
            for (int i = 0; i < 32; ++i) U[(K0+i)*DD + gc] = y[i];
          }
          float* dstl = half ? Uc : Ur;
          #pragma unroll
          for (int i = 0; i < 32; ++i) dstl[i*64 + cc] = act ? y[i] : 0.f;
        }
        __syncthreads();

        // (c) trailing rank-32 update for this 64x64 tile
        int tr = (tid >> 4) * 4;
        int tc = (tid & 15) * 4;
        float acc[4][4] = {};
        #pragma unroll
        for (int k = 0; k < 32; ++k){
          f32x4 a = *(const f32x4*)&Ur[k*64 + tr];
          f32x4 bfv = *(const f32x4*)&Uc[k*64 + tc];
          #pragma unroll
          for (int ii = 0; ii < 4; ++ii)
            #pragma unroll
            for (int jj = 0; jj < 4; ++jj)
              acc[ii][jj] += a[ii]*bfv[jj];
        }
        #pragma unroll
        for (int ii = 0; ii < 4; ++ii){
          int gi = r0 + tr + ii;
          if (gi < 256){
            #pragma unroll
            for (int jj = 0; jj < 4; ++jj){
              int gj = c0 + tc + jj;
              if (gj < 256 && gj >= gi)
                G[gi*DD + gj] -= acc[ii][jj];
            }
          }
        }
        __syncthreads();   // LDS reuse safety before next kb
      }
    }
    grid.sync();
  }

  // ---- Phase B: row-parallel TRSM Q·R = A (R from shadow U) ----
  {
    int w = tid >> 6;
    int c = blockIdx.x*64 + lane;
    const float* arow = wg + (size_t)c*DD;

    for (int J = 0; J < 8; ++J){
      int J0 = J*32;
      int nrows8 = (J0 + 32)*8;
      for (int idx = tid; idx < nrows8; idx += 256){
        int row = idx >> 3, q = idx & 7;
        *(f32x4*)&Pp[row*32 + q*4] = *(const f32x4*)&U[row*256 + J0 + q*4];
      }
      __syncthreads();

      float W[32];
      if (w == 0){
        #pragma unroll
        for (int r = 0; r < 32; ++r) W[r] = arow[J0 + r] + 1e-8f;
      } else {
        #pragma unroll
        for (int r = 0; r < 32; ++r) W[r] = 0.f;
      }
      for (int M = w; M < J; M += 4){
        #pragma unroll 4
        for (int k = 0; k < 32; ++k){
          int row = M*32 + k;
          float qv = Qlds[row*64 + lane];
          const float* pr = &Pp[row*32];
          #pragma unroll
          for (int r4 = 0; r4 < 8; ++r4){
            f32x4 p = *(const f32x4*)&pr[r4*4];
            W[r4*4+0] -= qv*p[0];
            W[r4*4+1] -= qv*p[1];
            W[r4*4+2] -= qv*p[2];
            W[r4*4+3] -= qv*p[3];
          }
        }
      }
      if (w > 0){
        #pragma unroll
        for (int r = 0; r < 32; ++r) Wred[((w-1)*32 + r)*64 + lane] = W[r];
      }
      __syncthreads();

      if (w == 0){
        #pragma unroll
        for (int r = 0; r < 32; ++r)
          W[r] += Wred[r*64 + lane] + Wred[(32+r)*64 + lane] + Wred[(64+r)*64 + lane];
        #pragma unroll
        for (int i = 0; i < 32; ++i){
          float t = W[i];
          for (int l = 0; l < i; ++l) t -= W[l] * Pp[(J0 + l)*32 + i];
          W[i] = t / Pp[(J0 + i)*32 + i];
        }
        #pragma unroll
        for (int i = 0; i < 32; ++i) Qlds[(J0 + i)*64 + lane] = W[i];
        #pragma unroll
        for (int r4 = 0; r4 < 8; ++r4){
          f32x4 q4; u16x4 qb4;
          #pragma unroll
          for (int jj = 0; jj < 4; ++jj){ q4[jj] = W[r4*4+jj]; qb4[jj] = f2b(W[r4*4+jj]); }
          *(f32x4*)&Q[(size_t)c*DD + J0 + r4*4] = q4;
          *(u16x4*)&Qb[(size_t)c*DD + J0 + r4*4] = qb4;
        }
        #pragma unroll
        for (int i = 0; i < 32; ++i){
          float qs = W[i] * INV_SQRT_C;
          Qst[(size_t)(J0 + i)*CC + c] = qs;
          Qstb[(size_t)(J0 + i)*CC + c] = f2b(qs);
        }
      }
      __syncthreads();
    }
  }
}

// quadratic form via wave-per-row coalesced reads; bf16 outputs only.
__global__ __launch_bounds__(256) void k_fold(const float* __restrict__ Wg, const float* __restrict__ Wc,
    const float* __restrict__ gamg, const float* __restrict__ betg,
    const float* __restrict__ gamc, const float* __restrict__ betc,
    const float* __restrict__ S, const float* __restrict__ xbar,
    float* __restrict__ bgf, float* __restrict__ bcf,
    u16* __restrict__ Wgb, u16* __restrict__ Wcb){
  int o = blockIdx.x & 511, br = blockIdx.x >> 9;
  int tid = threadIdx.x;
  int wv = tid >> 6, lane = tid & 63;
  const float* W = br ? Wc : Wg;
  __shared__ float wrow[512];
  __shared__ float red[256];
  __shared__ float yred[4];
  __shared__ float sc_s, bi_s;
  wrow[tid] = W[o*512 + tid]; wrow[tid+256] = W[o*512 + tid + 256];
  __syncthreads();

  float qp = 0.f;
  for (int c1 = wv; c1 < 512; c1 += 4){
    const float* srow = S + (size_t)c1*512;
    float y = 0.f;
    #pragma unroll
    for (int c8 = 0; c8 < 8; ++c8){
      int c2 = lane + c8*64;
      y = fmaf(srow[c2], wrow[c2], y);
    }
    y += __shfl_xor(y, 1);
    y += __shfl_xor(y, 2);
    y += __shfl_xor(y, 4);
    y += __shfl_xor(y, 8);
    y += __shfl_xor(y, 16);
    y += __shfl_xor(y, 32);
    qp = fmaf(wrow[c1], y, qp);
  }
  if (lane == 0) yred[wv] = qp;

  float mp = 0.f;
  for (int c = tid; c < 512; c += 256) mp = fmaf(wrow[c], xbar[c], mp);
  red[tid] = mp; __syncthreads();
  for (int st = 128; st; st >>= 1){
    if (tid < st) red[tid] += red[tid+st];
    __syncthreads();
  }
  if (tid == 0){
    float m = red[0];
    float E = (yred[0] + yred[1] + yred[2] + yred[3]) * (1.0f/(float)NPIX);
    float var = E - m*m;
    float rstd = rsqrtf(var + 1e-5f);
    float gma = br ? gamc[o] : gamg[o];
    float bta = br ? betc[o] : betg[o];
    sc_s = gma * rstd;
    bi_s = bta - gma * rstd * m;
  }
  __syncthreads();
  float* bf = br ? bcf : bgf;
  u16* Wb  = br ? Wcb : Wgb;
  Wb[o*512 + tid]     = f2b(sc_s * wrow[tid]);
  Wb[o*512 + tid+256] = f2b(sc_s * wrow[tid+256]);
  if (tid == 0) bf[o] = bi_s;
}

// bv hoisted; async staging (issue all 64 loads, then LDS writes).
__global__ __launch_bounds__(512) void k_gconv(const float* __restrict__ x,
    const u16* __restrict__ Wb, const float* __restrict__ bf, float* __restrict__ gpart){
  __shared__ __align__(16) u16 Xs[64*512];
  int tid = threadIdx.x;
  int w = tid >> 6, lane = tid & 63, lr = lane & 15, g = lane >> 4;
  int slab = blockIdx.x, b = blockIdx.y;
  int p0 = slab*64;

  {
    const float* xb = x + (size_t)b*CC*HWP + p0;
    int p = tid & 63;
    int c8 = (tid >> 6) * 8;
    float v[64];
    #pragma unroll
    for (int pass = 0; pass < 8; ++pass)
      #pragma unroll
      for (int i = 0; i < 8; ++i)
        v[pass*8 + i] = xb[(size_t)(c8 + pass*64 + i)*HWP + p];
    #pragma unroll
    for (int pass = 0; pass < 8; ++pass){
      u16x8 u;
      #pragma unroll
      for (int i = 0; i < 8; ++i) u[i] = f2b(v[pass*8 + i]);
      *(u16x8*)&Xs[p*512 + ((c8 + pass*64) ^ ((p & 7) << 3))] = u;
    }
  }
  __syncthreads();

  f32x4 acc[4][4] = {};
  for (int k = 0; k < 16; ++k){
    int c0 = k*32 + g*8;
    s16x8 bv[4];
    #pragma unroll
    for (int pt = 0; pt < 4; ++pt){
      int p = pt*16 + lr;
      bv[pt] = *(const s16x8*)&Xs[p*512 + (c0 ^ ((p & 7) << 3))];
    }
    #pragma unroll
    for (int i = 0; i < 4; ++i){
      int o0 = (w*4 + i)*16;
      s16x8 a = *(const s16x8*)(Wb + (size_t)(o0 + lr)*512 + c0);
      #pragma unroll
      for (int pt = 0; pt < 4; ++pt)
        acc[i][pt] = mfma16(a, bv[pt], acc[i][pt]);
    }
  }
  #pragma unroll
  for (int i = 0; i < 4; ++i){
    int o0 = (w*4 + i)*16;
    f32x4 bias4 = *(const f32x4*)(bf + o0 + 4*g);
    float s[4] = {0.f, 0.f, 0.f, 0.f};
    #pragma unroll
    for (int pt = 0; pt < 4; ++pt)
      #pragma unroll
      for (int r = 0; r < 4; ++r)
        s[r] += fmaxf(acc[i][pt][r] + bias4[r], 0.f);
    #pragma unroll
    for (int r = 0; r < 4; ++r){
      s[r] += __shfl_xor(s[r], 1);
      s[r] += __shfl_xor(s[r], 2);
      s[r] += __shfl_xor(s[r], 4);
      s[r] += __shfl_xor(s[r], 8);
    }
    if (lr == 0){
      f32x4 sv; sv[0]=s[0]; sv[1]=s[1]; sv[2]=s[2]; sv[3]=s[3];
      *(f32x4*)(gpart + (size_t)(b*64 + slab)*512 + o0 + 4*g) = sv;
    }
  }
}

__global__ __launch_bounds__(256) void k_gvec(const float* __restrict__ gpart, const float* __restrict__ Q,
    const float* __restrict__ Qst, float* __restrict__ gvec){
  int b = blockIdx.x, tid = threadIdx.x;
  __shared__ float g0[512];
  __shared__ float aff[256];
  __shared__ float red[256];
  for (int o = tid; o < 512; o += 256){
    float s = 0.f;
    for (int sl = 0; sl < 64; ++sl) s += gpart[(size_t)(b*64 + sl)*512 + o];
    g0[o] = s * (1.0f/4096.0f);
  }
  __syncthreads();
  float l = 0.f;
  { const float* qr = Qst + (size_t)tid*512;
    for (int c = 0; c < 512; ++c) l = fmaf(qr[c], g0[c], l); }
  red[tid] = l; __syncthreads();
  for (int st = 128; st; st >>= 1){ if (tid < st) red[tid] = fmaxf(red[tid], red[tid+st]); __syncthreads(); }
  float m = red[0]; __syncthreads();
  float e = expf(l - m);
  red[tid] = e; __syncthreads();
  for (int st = 128; st; st >>= 1){ if (tid < st) red[tid] += red[tid+st]; __syncthreads(); }
  float inv = 1.0f/red[0];
  aff[tid] = e * inv;
  __syncthreads();
  for (int o = tid; o < 512; o += 256){
    const float* qr = Q + (size_t)o*DD;
    float v = 0.f;
    for (int d = 0; d < DD; ++d) v = fmaf(aff[d], qr[d], v);
    gvec[b*512 + o] = 1.0f/(1.0f + expf(-v));
  }
}

// v6 (best measured): 64px tile, 512 threads; async staging + L2-hot residual.
__global__ __launch_bounds__(512) void k_fused(const float* __restrict__ x,
    const u16* __restrict__ Wcb, const float* __restrict__ bcf,
    const u16* __restrict__ Qstb, const u16* __restrict__ Qb,
    const float* __restrict__ gvec, float* __restrict__ out){
  __shared__ __align__(16) u16 Xs[64*512];
  __shared__ __align__(16) u16 Ts[64*512];
  float* Lsf = (float*)Xs;
  u16*   As  = Ts;
  int tid = threadIdx.x;
  int w = tid >> 6, lane = tid & 63, lr = lane & 15, g = lane >> 4;
  int b = blockIdx.y, p0 = blockIdx.x*64;

  float xr[64];
  {
    const float* xb = x + (size_t)b*CC*HWP + p0;
    int p = tid & 63;
    int c8 = (tid >> 6) * 8;
    float v[64];
    #pragma unroll
    for (int pass = 0; pass < 8; ++pass)
      #pragma unroll
      for (int i = 0; i < 8; ++i)
        v[pass*8 + i] = xb[(size_t)(c8 + pass*64 + i)*HWP + p];
    #pragma unroll
    for (int pass = 0; pass < 8; ++pass){
      u16x8 u;
      #pragma unroll
      for (int i = 0; i < 8; ++i) u[i] = f2b(v[pass*8 + i]);
      *(u16x8*)&Xs[p*512 + ((c8 + pass*64) ^ ((p & 7) << 3))] = u;
    }
    #pragma unroll
    for (int i = 0; i < 4; ++i)
      #pragma unroll
      for (int pt = 0; pt < 4; ++pt)
        #pragma unroll
        for (int r = 0; r < 4; ++r)
          xr[(i*4 + pt)*4 + r] =
            x[(size_t)(b*CC + (w*4 + i)*16 + 4*g + r)*HWP + p0 + pt*16 + lr];
  }
  __syncthreads();

  // phase 1: T = relu(Wc.X + b) -> Ts
  {
    f32x4 acc[4][4] = {};
    for (int k = 0; k < 16; ++k){
      int c0 = k*32 + g*8;
      s16x8 bv[4];
      #pragma unroll
      for (int pt = 0; pt < 4; ++pt){
        int p = pt*16 + lr;
        bv[pt] = *(const s16x8*)&Xs[p*512 + (c0 ^ ((p & 7) << 3))];
      }
      #pragma unroll
      for (int i = 0; i < 4; ++i){
        int o0 = (w*4 + i)*16;
        s16x8 a = *(const s16x8*)(Wcb + (size_t)(o0 + lr)*512 + c0);
        #pragma unroll
        for (int pt = 0; pt < 4; ++pt)
          acc[i][pt] = mfma16(a, bv[pt], acc[i][pt]);
      }
    }
    #pragma unroll
    for (int i = 0; i < 4; ++i){
      int o0 = (w*4 + i)*16;
      f32x4 bias4 = *(const f32x4*)(bcf + o0 + 4*g);
      #pragma unroll
      for (int pt = 0; pt < 4; ++pt){
        int p = pt*16 + lr;
        u16x4 u;
        #pragma unroll
        for (int r = 0; r < 4; ++r) u[r] = f2b(fmaxf(acc[i][pt][r] + bias4[r], 0.f));
        *(u16x4*)&Ts[p*512 + ((o0 + 4*g) ^ ((p & 7) << 3))] = u;
      }
    }
  }
  __syncthreads();

  // phase 2: L = Qst.T -> Lsf (overlays Xs)
  {
    f32x4 acc[2][4] = {};
    for (int k = 0; k < 16; ++k){
      int o0 = k*32 + g*8;
      s16x8 bv[4];
      #pragma unroll
      for (int pt = 0; pt < 4; ++pt){
        int p = pt*16 + lr;
        bv[pt] = *(const s16x8*)&Ts[p*512 + (o0 ^ ((p & 7) << 3))];
      }
      #pragma unroll
      for (int i = 0; i < 2; ++i){
        int d0 = (w*2 + i)*16;
        s16x8 a = *(const s16x8*)(Qstb + (size_t)(d0 + lr)*512 + o0);
        #pragma unroll
        for (int pt = 0; pt < 4; ++pt)
          acc[i][pt] = mfma16(a, bv[pt], acc[i][pt]);
      }
    }
    #pragma unroll
    for (int i = 0; i < 2; ++i){
      int d0 = (w*2 + i)*16;
      #pragma unroll
      for (int pt = 0; pt < 4; ++pt){
        int p = pt*16 + lr;
        *(f32x4*)&Lsf[p*256 + ((d0 + 4*g) ^ ((p & 7) << 2))] = acc[i][pt];
      }
    }
  }
  __syncthreads();

  // phase 3: softmax over d per pixel -> As (overlays Ts)
  {
    int px = tid >> 3, sub = tid & 7;
    float* Lrow = Lsf + px*256;
    int sw2 = (px & 7) << 2, sw3 = (px & 7) << 3;
    float v[32];
    #pragma unroll
    for (int jj = 0; jj < 8; ++jj){
      int d0 = sub*32 + jj*4;
      f32x4 t = *(const f32x4*)&Lrow[d0 ^ sw2];
      v[jj*4+0] = t[0]; v[jj*4+1] = t[1]; v[jj*4+2] = t[2]; v[jj*4+3] = t[3];
    }
    float m = v[0];
    #pragma unroll
    for (int jj = 1; jj < 32; ++jj) m = fmaxf(m, v[jj]);
    m = fmaxf(m, __shfl_xor(m, 1));
    m = fmaxf(m, __shfl_xor(m, 2));
    m = fmaxf(m, __shfl_xor(m, 4));
    float s = 0.f;
    #pragma unroll
    for (int jj = 0; jj < 32; ++jj){ v[jj] = __expf(v[jj] - m); s += v[jj]; }
    s += __shfl_xor(s, 1);
    s += __shfl_xor(s, 2);
    s += __shfl_xor(s, 4);
    float inv = 1.0f/s;
    #pragma unroll
    for (int jj = 0; jj < 4; ++jj){
      int d0 = sub*32 + jj*8;
      u16x8 u;
      #pragma unroll
      for (int i = 0; i < 8; ++i) u[i] = f2b(v[jj*8+i] * inv);
      *(u16x8*)&As[px*256 + (d0 ^ sw3)] = u;
    }
  }
  __syncthreads();

  // phase 4: ch = Q.A ; out = ch*g + x
  {
    f32x4 acc[4][4] = {};
    for (int k = 0; k < 8; ++k){
      int d0 = k*32 + g*8;
      s16x8 bv[4];
      #pragma unroll
      for (int pt = 0; pt < 4; ++pt){
        int p = pt*16 + lr;
        bv[pt] = *(const s16x8*)&As[p*256 + (d0 ^ ((p & 7) << 3))];
      }
      #pragma unroll
      for (int i = 0; i < 4; ++i){
        int o0 = (w*4 + i)*16;
        s16x8 a = *(const s16x8*)(Qb + (size_t)(o0 + lr)*256 + d0);
        #pragma unroll
        for (int pt = 0; pt < 4; ++pt)
          acc[i][pt] = mfma16(a, bv[pt], acc[i][pt]);
      }
    }
    #pragma unroll
    for (int i = 0; i < 4; ++i){
      int o0 = (w*4 + i)*16;
      f32x4 gg = *(const f32x4*)(gvec + b*512 + o0 + 4*g);
      #pragma unroll
      for (int pt = 0; pt < 4; ++pt){
        #pragma unroll
        for (int r = 0; r < 4; ++r){
          size_t idx = (size_t)(b*CC + o0 + 4*g + r)*HWP + p0 + pt*16 + lr;
          out[idx] = fmaf(acc[i][pt][r], gg[r], xr[(i*4 + pt)*4 + r]);
        }
      }
    }
  }
}

extern "C" void kernel_launch(void* const* d_in, const int* in_sizes, int n_in,
                              void* d_out, int out_size, void* d_ws, size_t ws_size,
                              hipStream_t stream) {
  const float* x    = (const float*)d_in[0];
  const float* wg   = (const float*)d_in[1];
  const float* Wg   = (const float*)d_in[2];
  const float* gamg = (const float*)d_in[3];
  const float* betg = (const float*)d_in[4];
  const float* Wc   = (const float*)d_in[5];
  const float* gamc = (const float*)d_in[6];
  const float* betc = (const float*)d_in[7];
  float* out = (float*)d_out;

  int kspl = 1;
  {
    size_t base = (size_t)1320448 + 524288 + 393216;
    if (ws_size >= (base + (size_t)2*16*262144) * 4) kspl = 2;
  }

  float* ws = (float*)d_ws;
  float* G     = ws + 0;
  float* U     = ws + 65536;
  float* Q     = ws + 131072;
  float* Qst   = ws + 262144;
  float* S     = ws + 393216;
  float* xbar  = ws + 655360;
  float* bgf   = ws + 918016;
  float* bcf   = ws + 1180672;
  float* gvec  = ws + 1181184;
  float* Spart = ws + 1320448;
  float* gpart = Spart + (size_t)kspl*16*262144;
  u16*   ub    = (u16*)(gpart + 524288);
  u16* Qb   = ub;
  u16* Qstb = ub + 131072;
  u16* Wgb  = ub + 262144;
  u16* Wcb  = ub + 524288;

  hipMemsetAsync(xbar, 0, 512*sizeof(float), stream);
  k_gram<<<dim3(10,16,kspl), 512, 0, stream>>>(x, Spart, xbar, kspl);
  k_sredG<<<1280, 256, 0, stream>>>(Spart, S, 16*kspl, wg, G);
  {
    void* qrArgs[] = {(void*)&G, (void*)&U, (void*)&wg, (void*)&Q, (void*)&Qst,
                      (void*)&Qb, (void*)&Qstb};
    hipLaunchCooperativeKernel((void*)k_qr, dim3(8), dim3(256), qrArgs, 0, stream);
  }
  k_fold<<<1024, 256, 0, stream>>>(Wg, Wc, gamg, betg, gamc, betc, S, xbar, bgf, bcf, Wgb, Wcb);
  k_gconv<<<dim3(64,16), 512, 0, stream>>>(x, Wgb, bgf, gpart);
  k_gvec<<<16, 256, 0, stream>>>(gpart, Q, Qst, gvec);
  k_fused<<<dim3(64,16), 512, 0, stream>>>(x, Wcb, bcf, Qstb, Qb, gvec, out);
}

// Round 20
// 820.233 us; speedup vs baseline: 1.0433x; 1.0433x over previous
//
#include <hip/hip_runtime.h>
#include <hip/hip_bf16.h>

#define BB 16
#define CC 512
#define HWP 4096
#define DD 256
#define NPIX 65536
#define INV_SQRT_C 0.04419417382415922f

typedef unsigned short u16;
typedef __attribute__((ext_vector_type(8))) short s16x8;
typedef __attribute__((ext_vector_type(8))) unsigned short u16x8;
typedef __attribute__((ext_vector_type(4))) unsigned short u16x4;
typedef __attribute__((ext_vector_type(4))) float f32x4;

__device__ __forceinline__ u16 f2b(float f){
  unsigned int u = __builtin_bit_cast(unsigned int, f);
  unsigned int r = (u + 0x7fffu + ((u >> 16) & 1u)) >> 16;
  return (u16)r;
}

__device__ __forceinline__ f32x4 mfma16(s16x8 a, s16x8 b, f32x4 c){
  return __builtin_amdgcn_mfma_f32_16x16x32_bf16(a, b, c, 0, 0, 0);
}

// S = sum_b X_b X_b^T via MFMA bf16. 128x128 tiles, upper tile-pairs (10),
// K-step 64 + split-K. Diagonal tiles ALSO accumulate xbar (channel sums).
__global__ __launch_bounds__(512) void k_gram(const float* __restrict__ x, float* __restrict__ Spart,
                                              float* __restrict__ xbar, int kspl){
  __shared__ __align__(16) u16 Asl[128*72];
  __shared__ __align__(16) u16 Bsl[128*72];
  int tid = threadIdx.x;
  int w = tid >> 6, lane = tid & 63, lr = lane & 15, g = lane >> 4;
  int b = blockIdx.y;
  int kz = blockIdx.z;
  int t = blockIdx.x, ti = 0, rem = 4;
  while (t >= rem){ t -= rem; ++ti; --rem; }
  int tj = ti + t;
  int r0 = ti*128, c0 = tj*128;
  bool isdiag = (ti == tj);
  int wm = w >> 2, wn = w & 3;
  f32x4 acc[4][2] = {};
  float xsum[8] = {};
  const float* xb = x + (size_t)b*CC*HWP;
  int klen = HWP / kspl;
  int kbase = kz * klen;
  for (int k0 = kbase; k0 < kbase + klen; k0 += 64){
    __syncthreads();
    #pragma unroll
    for (int s = 0; s < 8; ++s){
      int tt = tid + s*512;
      int arr = tt >> 11;
      int row = (tt >> 4) & 127;
      int q = tt & 15;
      const float* src = xb + (size_t)((arr ? c0 : r0) + row)*HWP + k0 + q*4;
      f32x4 v = *(const f32x4*)src;
      if (isdiag && arr == 0) xsum[s] += (v[0]+v[1]) + (v[2]+v[3]);
      u16x4 u; u[0]=f2b(v[0]); u[1]=f2b(v[1]); u[2]=f2b(v[2]); u[3]=f2b(v[3]);
      u16* dst = (arr ? Bsl : Asl) + row*72 + q*4;
      *(u16x4*)dst = u;
    }
    __syncthreads();
    #pragma unroll
    for (int kc = 0; kc < 2; ++kc){
      s16x8 av[4], bv[2];
      #pragma unroll
      for (int mt = 0; mt < 4; ++mt) av[mt] = *(const s16x8*)&Asl[(wm*64 + mt*16 + lr)*72 + kc*32 + g*8];
      #pragma unroll
      for (int nt = 0; nt < 2; ++nt) bv[nt] = *(const s16x8*)&Bsl[(wn*32 + nt*16 + lr)*72 + kc*32 + g*8];
      #pragma unroll
      for (int mt = 0; mt < 4; ++mt)
        #pragma unroll
        for (int nt = 0; nt < 2; ++nt)
          acc[mt][nt] = mfma16(av[mt], bv[nt], acc[mt][nt]);
    }
  }
  float* sp = Spart + (size_t)(b*kspl + kz)*262144;
  #pragma unroll
  for (int mt = 0; mt < 4; ++mt)
    #pragma unroll
    for (int nt = 0; nt < 2; ++nt)
      #pragma unroll
      for (int r = 0; r < 4; ++r)
        sp[(size_t)(r0 + wm*64 + mt*16 + 4*g + r)*512 + c0 + wn*32 + nt*16 + lr] = acc[mt][nt][r];

  if (isdiag){
    __syncthreads();
    float* scr = (float*)Asl;
    #pragma unroll
    for (int s = 0; s < 8; ++s){
      int tt = tid + s*512;
      if ((tt >> 11) == 0){
        int row = (tt >> 4) & 127, q = tt & 15;
        scr[row*16 + q] = xsum[s];
      }
    }
    __syncthreads();
    if (tid < 128){
      float rs = 0.f;
      #pragma unroll
      for (int j = 0; j < 16; ++j) rs += scr[tid*16 + j];
      atomicAdd(&xbar[r0 + tid], rs * (1.0f/(float)NPIX));
    }
  }
}

// merged: blocks 0..1023 = sreduce (slot sum + mirror); blocks 1024..1279 = G rows
__global__ __launch_bounds__(256) void k_sredG(const float* __restrict__ Spart, float* __restrict__ S,
                                               int nslots, const float* __restrict__ wg, float* __restrict__ G){
  if (blockIdx.x < 1024){
    int idx = blockIdx.x*256 + threadIdx.x;
    int i = idx >> 9, j = idx & 511;
    int src = ((i >> 7) <= (j >> 7)) ? idx : (j*512 + i);
    float s = 0.f;
    for (int k = 0; k < nslots; ++k) s += Spart[(size_t)k*262144 + src];
    S[idx] = s;
  } else {
    int i = blockIdx.x - 1024, j = threadIdx.x;
    float s = 0.f;
    for (int c = 0; c < CC; ++c)
      s = fmaf(wg[c*DD + i] + 1e-8f, wg[c*DD + j] + 1e-8f, s);
    G[i*DD + j] = s;
  }
}

// Merged Cholesky step kb (diag in registers, panel solve, trail tile).
__global__ __launch_bounds__(256) void k_cholStep(float* __restrict__ G, float* __restrict__ U, int kb){
  __shared__ __align__(16) float Ur[32][64];
  __shared__ __align__(16) float Uc[32][64];
  int tid = threadIdx.x;
  int lane = tid & 63;
  int j = lane & 31;
  int K0 = kb*32;
  int nt = 256 - K0 - 32;
  int T = (nt + 63) >> 6;
  int t = blockIdx.x, ti = 0, rem = T;
  while (nt > 0 && t >= rem){ t -= rem; ++ti; --rem; }
  int tj = ti + t;
  int r0 = K0 + 32 + ti*64;
  int c0 = K0 + 32 + tj*64;

  float c[32];
  #pragma unroll
  for (int i = 0; i < 32; ++i)
    c[i] = (i <= j) ? G[(K0+i)*DD + K0 + j] : 0.f;
  #pragma unroll
  for (int k = 0; k < 32; ++k){
    float piv = __shfl(c[k], k);
    float sd = sqrtf(piv);
    float ukj = c[k] / sd;
    c[k] = ukj;
    float uk[32];
    #pragma unroll
    for (int i = k + 1; i < 32; ++i) uk[i] = __shfl(ukj, i);
    #pragma unroll
    for (int i = k + 1; i < 32; ++i) c[i] -= uk[i] * ukj;
  }
  if (blockIdx.x == 0 && tid < 32){
    #pragma unroll
    for (int i = 0; i < 32; ++i)
      if (i <= j) U[(K0+i)*DD + K0 + j] = c[i];
  }
  if (nt <= 0) return;

  if (tid < 128){
    int half = tid >> 6;
    int cc = tid & 63;
    int gc = (half ? c0 : r0) + cc;
    bool act = gc < 256;
    float y[32];
    #pragma unroll
    for (int i = 0; i < 32; ++i) y[i] = act ? G[(K0+i)*DD + gc] : 0.f;
    #pragma unroll
    for (int i = 0; i < 32; ++i){
      float s0 = y[i];
      #pragma unroll
      for (int l = 0; l < 32; ++l)
        if (l < i) s0 -= __shfl(c[l], i) * y[l];
      y[i] = s0 / __shfl(c[i], i);
    }
    if (act){
      #pragma unroll
      for (int i = 0; i < 32; ++i) U[(K0+i)*DD + gc] = y[i];
    }
    if (half){
      #pragma unroll
      for (int i = 0; i < 32; ++i) Uc[i][cc] = act ? y[i] : 0.f;
    } else {
      #pragma unroll
      for (int i = 0; i < 32; ++i) Ur[i][cc] = act ? y[i] : 0.f;
    }
  }
  __syncthreads();

  int tr = (tid >> 4) * 4;
  int tc = (tid & 15) * 4;
  float acc[4][4] = {};
  #pragma unroll
  for (int k = 0; k < 32; ++k){
    f32x4 a = *(const f32x4*)&Ur[k][tr];
    f32x4 b = *(const f32x4*)&Uc[k][tc];
    #pragma unroll
    for (int ii = 0; ii < 4; ++ii)
      #pragma unroll
      for (int jj = 0; jj < 4; ++jj)
        acc[ii][jj] += a[ii]*b[jj];
  }
  #pragma unroll
  for (int ii = 0; ii < 4; ++ii){
    int gi = r0 + tr + ii;
    if (gi >= 256) continue;
    #pragma unroll
    for (int jj = 0; jj < 4; ++jj){
      int gj = c0 + tc + jj;
      if (gj < 256 && gj >= gi)
        G[gi*DD + gj] -= acc[ii][jj];
    }
  }
}

// Row-parallel TRSM: Q·R = A (R read from shadow U). 8 blocks x 256 threads.
__global__ __launch_bounds__(256) void k_qsolve(const float* __restrict__ U,
    const float* __restrict__ wg,
    float* __restrict__ Q, float* __restrict__ Qst,
    u16* __restrict__ Qb, u16* __restrict__ Qstb){
  __shared__ __align__(16) float Pp[8192];
  __shared__ float Qlds[256*64];
  __shared__ float Wred[3*32*64];
  int tid = threadIdx.x;
  int w = tid >> 6, lane = tid & 63;
  int c = blockIdx.x*64 + lane;
  const float* arow = wg + (size_t)c*DD;

  for (int J = 0; J < 8; ++J){
    int J0 = J*32;
    int nrows8 = (J0 + 32)*8;
    for (int idx = tid; idx < nrows8; idx += 256){
      int row = idx >> 3, q = idx & 7;
      *(f32x4*)&Pp[row*32 + q*4] = *(const f32x4*)&U[row*256 + J0 + q*4];
    }
    __syncthreads();

    float W[32];
    if (w == 0){
      #pragma unroll
      for (int r = 0; r < 32; ++r) W[r] = arow[J0 + r] + 1e-8f;
    } else {
      #pragma unroll
      for (int r = 0; r < 32; ++r) W[r] = 0.f;
    }
    for (int M = w; M < J; M += 4){
      #pragma unroll 4
      for (int k = 0; k < 32; ++k){
        int row = M*32 + k;
        float qv = Qlds[row*64 + lane];
        const float* pr = &Pp[row*32];
        #pragma unroll
        for (int r4 = 0; r4 < 8; ++r4){
          f32x4 p = *(const f32x4*)&pr[r4*4];
          W[r4*4+0] -= qv*p[0];
          W[r4*4+1] -= qv*p[1];
          W[r4*4+2] -= qv*p[2];
          W[r4*4+3] -= qv*p[3];
        }
      }
    }
    if (w > 0){
      #pragma unroll
      for (int r = 0; r < 32; ++r) Wred[((w-1)*32 + r)*64 + lane] = W[r];
    }
    __syncthreads();

    if (w == 0){
      #pragma unroll
      for (int r = 0; r < 32; ++r)
        W[r] += Wred[r*64 + lane] + Wred[(32+r)*64 + lane] + Wred[(64+r)*64 + lane];
      #pragma unroll
      for (int i = 0; i < 32; ++i){
        float t = W[i];
        for (int l = 0; l < i; ++l) t -= W[l] * Pp[(J0 + l)*32 + i];
        W[i] = t / Pp[(J0 + i)*32 + i];
      }
      #pragma unroll
      for (int i = 0; i < 32; ++i) Qlds[(J0 + i)*64 + lane] = W[i];
      #pragma unroll
      for (int r4 = 0; r4 < 8; ++r4){
        f32x4 q4; u16x4 qb4;
        #pragma unroll
        for (int jj = 0; jj < 4; ++jj){ q4[jj] = W[r4*4+jj]; qb4[jj] = f2b(W[r4*4+jj]); }
        *(f32x4*)&Q[(size_t)c*DD + J0 + r4*4] = q4;
        *(u16x4*)&Qb[(size_t)c*DD + J0 + r4*4] = qb4;
      }
      #pragma unroll
      for (int i = 0; i < 32; ++i){
        float qs = W[i] * INV_SQRT_C;
        Qst[(size_t)(J0 + i)*CC + c] = qs;
        Qstb[(size_t)(J0 + i)*CC + c] = f2b(qs);
      }
    }
    __syncthreads();
  }
}

// quadratic form via wave-per-row coalesced reads; bf16 outputs only.
__global__ __launch_bounds__(256) void k_fold(const float* __restrict__ Wg, const float* __restrict__ Wc,
    const float* __restrict__ gamg, const float* __restrict__ betg,
    const float* __restrict__ gamc, const float* __restrict__ betc,
    const float* __restrict__ S, const float* __restrict__ xbar,
    float* __restrict__ bgf, float* __restrict__ bcf,
    u16* __restrict__ Wgb, u16* __restrict__ Wcb){
  int o = blockIdx.x & 511, br = blockIdx.x >> 9;
  int tid = threadIdx.x;
  int wv = tid >> 6, lane = tid & 63;
  const float* W = br ? Wc : Wg;
  __shared__ float wrow[512];
  __shared__ float red[256];
  __shared__ float yred[4];
  __shared__ float sc_s, bi_s;
  wrow[tid] = W[o*512 + tid]; wrow[tid+256] = W[o*512 + tid + 256];
  __syncthreads();

  float qp = 0.f;
  for (int c1 = wv; c1 < 512; c1 += 4){
    const float* srow = S + (size_t)c1*512;
    float y = 0.f;
    #pragma unroll
    for (int c8 = 0; c8 < 8; ++c8){
      int c2 = lane + c8*64;
      y = fmaf(srow[c2], wrow[c2], y);
    }
    y += __shfl_xor(y, 1);
    y += __shfl_xor(y, 2);
    y += __shfl_xor(y, 4);
    y += __shfl_xor(y, 8);
    y += __shfl_xor(y, 16);
    y += __shfl_xor(y, 32);
    qp = fmaf(wrow[c1], y, qp);
  }
  if (lane == 0) yred[wv] = qp;

  float mp = 0.f;
  for (int c = tid; c < 512; c += 256) mp = fmaf(wrow[c], xbar[c], mp);
  red[tid] = mp; __syncthreads();
  for (int st = 128; st; st >>= 1){
    if (tid < st) red[tid] += red[tid+st];
    __syncthreads();
  }
  if (tid == 0){
    float m = red[0];
    float E = (yred[0] + yred[1] + yred[2] + yred[3]) * (1.0f/(float)NPIX);
    float var = E - m*m;
    float rstd = rsqrtf(var + 1e-5f);
    float gma = br ? gamc[o] : gamg[o];
    float bta = br ? betc[o] : betg[o];
    sc_s = gma * rstd;
    bi_s = bta - gma * rstd * m;
  }
  __syncthreads();
  float* bf = br ? bcf : bgf;
  u16* Wb  = br ? Wcb : Wgb;
  Wb[o*512 + tid]     = f2b(sc_s * wrow[tid]);
  Wb[o*512 + tid+256] = f2b(sc_s * wrow[tid+256]);
  if (tid == 0) bf[o] = bi_s;
}

// bv hoisted; async staging (issue all 64 loads, then LDS writes).
__global__ __launch_bounds__(512) void k_gconv(const float* __restrict__ x,
    const u16* __restrict__ Wb, const float* __restrict__ bf, float* __restrict__ gpart){
  __shared__ __align__(16) u16 Xs[64*512];
  int tid = threadIdx.x;
  int w = tid >> 6, lane = tid & 63, lr = lane & 15, g = lane >> 4;
  int slab = blockIdx.x, b = blockIdx.y;
  int p0 = slab*64;

  {
    const float* xb = x + (size_t)b*CC*HWP + p0;
    int p = tid & 63;
    int c8 = (tid >> 6) * 8;
    float v[64];
    #pragma unroll
    for (int pass = 0; pass < 8; ++pass)
      #pragma unroll
      for (int i = 0; i < 8; ++i)
        v[pass*8 + i] = xb[(size_t)(c8 + pass*64 + i)*HWP + p];
    #pragma unroll
    for (int pass = 0; pass < 8; ++pass){
      u16x8 u;
      #pragma unroll
      for (int i = 0; i < 8; ++i) u[i] = f2b(v[pass*8 + i]);
      *(u16x8*)&Xs[p*512 + ((c8 + pass*64) ^ ((p & 7) << 3))] = u;
    }
  }
  __syncthreads();

  f32x4 acc[4][4] = {};
  for (int k = 0; k < 16; ++k){
    int c0 = k*32 + g*8;
    s16x8 bv[4];
    #pragma unroll
    for (int pt = 0; pt < 4; ++pt){
      int p = pt*16 + lr;
      bv[pt] = *(const s16x8*)&Xs[p*512 + (c0 ^ ((p & 7) << 3))];
    }
    #pragma unroll
    for (int i = 0; i < 4; ++i){
      int o0 = (w*4 + i)*16;
      s16x8 a = *(const s16x8*)(Wb + (size_t)(o0 + lr)*512 + c0);
      #pragma unroll
      for (int pt = 0; pt < 4; ++pt)
        acc[i][pt] = mfma16(a, bv[pt], acc[i][pt]);
    }
  }
  #pragma unroll
  for (int i = 0; i < 4; ++i){
    int o0 = (w*4 + i)*16;
    f32x4 bias4 = *(const f32x4*)(bf + o0 + 4*g);
    float s[4] = {0.f, 0.f, 0.f, 0.f};
    #pragma unroll
    for (int pt = 0; pt < 4; ++pt)
      #pragma unroll
      for (int r = 0; r < 4; ++r)
        s[r] += fmaxf(acc[i][pt][r] + bias4[r], 0.f);
    #pragma unroll
    for (int r = 0; r < 4; ++r){
      s[r] += __shfl_xor(s[r], 1);
      s[r] += __shfl_xor(s[r], 2);
      s[r] += __shfl_xor(s[r], 4);
      s[r] += __shfl_xor(s[r], 8);
    }
    if (lr == 0){
      f32x4 sv; sv[0]=s[0]; sv[1]=s[1]; sv[2]=s[2]; sv[3]=s[3];
      *(f32x4*)(gpart + (size_t)(b*64 + slab)*512 + o0 + 4*g) = sv;
    }
  }
}

__global__ __launch_bounds__(256) void k_gvec(const float* __restrict__ gpart, const float* __restrict__ Q,
    const float* __restrict__ Qst, float* __restrict__ gvec){
  int b = blockIdx.x, tid = threadIdx.x;
  __shared__ float g0[512];
  __shared__ float aff[256];
  __shared__ float red[256];
  for (int o = tid; o < 512; o += 256){
    float s = 0.f;
    for (int sl = 0; sl < 64; ++sl) s += gpart[(size_t)(b*64 + sl)*512 + o];
    g0[o] = s * (1.0f/4096.0f);
  }
  __syncthreads();
  float l = 0.f;
  { const float* qr = Qst + (size_t)tid*512;
    for (int c = 0; c < 512; ++c) l = fmaf(qr[c], g0[c], l); }
  red[tid] = l; __syncthreads();
  for (int st = 128; st; st >>= 1){ if (tid < st) red[tid] = fmaxf(red[tid], red[tid+st]); __syncthreads(); }
  float m = red[0]; __syncthreads();
  float e = expf(l - m);
  red[tid] = e; __syncthreads();
  for (int st = 128; st; st >>= 1){ if (tid < st) red[tid] += red[tid+st]; __syncthreads(); }
  float inv = 1.0f/red[0];
  aff[tid] = e * inv;
  __syncthreads();
  for (int o = tid; o < 512; o += 256){
    const float* qr = Q + (size_t)o*DD;
    float v = 0.f;
    for (int d = 0; d < DD; ++d) v = fmaf(aff[d], qr[d], v);
    gvec[b*512 + o] = 1.0f/(1.0f + expf(-v));
  }
}

// v6 (best measured): 64px tile, 512 threads; async staging + L2-hot residual.
__global__ __launch_bounds__(512) void k_fused(const float* __restrict__ x,
    const u16* __restrict__ Wcb, const float* __restrict__ bcf,
    const u16* __restrict__ Qstb, const u16* __restrict__ Qb,
    const float* __restrict__ gvec, float* __restrict__ out){
  __shared__ __align__(16) u16 Xs[64*512];
  __shared__ __align__(16) u16 Ts[64*512];
  float* Lsf = (float*)Xs;
  u16*   As  = Ts;
  int tid = threadIdx.x;
  int w = tid >> 6, lane = tid & 63, lr = lane & 15, g = lane >> 4;
  int b = blockIdx.y, p0 = blockIdx.x*64;

  float xr[64];
  {
    const float* xb = x + (size_t)b*CC*HWP + p0;
    int p = tid & 63;
    int c8 = (tid >> 6) * 8;
    float v[64];
    #pragma unroll
    for (int pass = 0; pass < 8; ++pass)
      #pragma unroll
      for (int i = 0; i < 8; ++i)
        v[pass*8 + i] = xb[(size_t)(c8 + pass*64 + i)*HWP + p];
    #pragma unroll
    for (int pass = 0; pass < 8; ++pass){
      u16x8 u;
      #pragma unroll
      for (int i = 0; i < 8; ++i) u[i] = f2b(v[pass*8 + i]);
      *(u16x8*)&Xs[p*512 + ((c8 + pass*64) ^ ((p & 7) << 3))] = u;
    }
    #pragma unroll
    for (int i = 0; i < 4; ++i)
      #pragma unroll
      for (int pt = 0; pt < 4; ++pt)
        #pragma unroll
        for (int r = 0; r < 4; ++r)
          xr[(i*4 + pt)*4 + r] =
            x[(size_t)(b*CC + (w*4 + i)*16 + 4*g + r)*HWP + p0 + pt*16 + lr];
  }
  __syncthreads();

  // phase 1: T = relu(Wc.X + b) -> Ts
  {
    f32x4 acc[4][4] = {};
    for (int k = 0; k < 16; ++k){
      int c0 = k*32 + g*8;
      s16x8 bv[4];
      #pragma unroll
      for (int pt = 0; pt < 4; ++pt){
        int p = pt*16 + lr;
        bv[pt] = *(const s16x8*)&Xs[p*512 + (c0 ^ ((p & 7) << 3))];
      }
      #pragma unroll
      for (int i = 0; i < 4; ++i){
        int o0 = (w*4 + i)*16;
        s16x8 a = *(const s16x8*)(Wcb + (size_t)(o0 + lr)*512 + c0);
        #pragma unroll
        for (int pt = 0; pt < 4; ++pt)
          acc[i][pt] = mfma16(a, bv[pt], acc[i][pt]);
      }
    }
    #pragma unroll
    for (int i = 0; i < 4; ++i){
      int o0 = (w*4 + i)*16;
      f32x4 bias4 = *(const f32x4*)(bcf + o0 + 4*g);
      #pragma unroll
      for (int pt = 0; pt < 4; ++pt){
        int p = pt*16 + lr;
        u16x4 u;
        #pragma unroll
        for (int r = 0; r < 4; ++r) u[r] = f2b(fmaxf(acc[i][pt][r] + bias4[r], 0.f));
        *(u16x4*)&Ts[p*512 + ((o0 + 4*g) ^ ((p & 7) << 3))] = u;
      }
    }
  }
  __syncthreads();

  // phase 2: L = Qst.T -> Lsf (overlays Xs)
  {
    f32x4 acc[2][4] = {};
    for (int k = 0; k < 16; ++k){
      int o0 = k*32 + g*8;
      s16x8 bv[4];
      #pragma unroll
      for (int pt = 0; pt < 4; ++pt){
        int p = pt*16 + lr;
        bv[pt] = *(const s16x8*)&Ts[p*512 + (o0 ^ ((p & 7) << 3))];
      }
      #pragma unroll
      for (int i = 0; i < 2; ++i){
        int d0 = (w*2 + i)*16;
        s16x8 a = *(const s16x8*)(Qstb + (size_t)(d0 + lr)*512 + o0);
        #pragma unroll
        for (int pt = 0; pt < 4; ++pt)
          acc[i][pt] = mfma16(a, bv[pt], acc[i][pt]);
      }
    }
    #pragma unroll
    for (int i = 0; i < 2; ++i){
      int d0 = (w*2 + i)*16;
      #pragma unroll
      for (int pt = 0; pt < 4; ++pt){
        int p = pt*16 + lr;
        *(f32x4*)&Lsf[p*256 + ((d0 + 4*g) ^ ((p & 7) << 2))] = acc[i][pt];
      }
    }
  }
  __syncthreads();

  // phase 3: softmax over d per pixel -> As (overlays Ts)
  {
    int px = tid >> 3, sub = tid & 7;
    float* Lrow = Lsf + px*256;
    int sw2 = (px & 7) << 2, sw3 = (px & 7) << 3;
    float v[32];
    #pragma unroll
    for (int jj = 0; jj < 8; ++jj){
      int d0 = sub*32 + jj*4;
      f32x4 t = *(const f32x4*)&Lrow[d0 ^ sw2];
      v[jj*4+0] = t[0]; v[jj*4+1] = t[1]; v[jj*4+2] = t[2]; v[jj*4+3] = t[3];
    }
    float m = v[0];
    #pragma unroll
    for (int jj = 1; jj < 32; ++jj) m = fmaxf(m, v[jj]);
    m = fmaxf(m, __shfl_xor(m, 1));
    m = fmaxf(m, __shfl_xor(m, 2));
    m = fmaxf(m, __shfl_xor(m, 4));
    float s = 0.f;
    #pragma unroll
    for (int jj = 0; jj < 32; ++jj){ v[jj] = __expf(v[jj] - m); s += v[jj]; }
    s += __shfl_xor(s, 1);
    s += __shfl_xor(s, 2);
    s += __shfl_xor(s, 4);
    float inv = 1.0f/s;
    #pragma unroll
    for (int jj = 0; jj < 4; ++jj){
      int d0 = sub*32 + jj*8;
      u16x8 u;
      #pragma unroll
      for (int i = 0; i < 8; ++i) u[i] = f2b(v[jj*8+i] * inv);
      *(u16x8*)&As[px*256 + (d0 ^ sw3)] = u;
    }
  }
  __syncthreads();

  // phase 4: ch = Q.A ; out = ch*g + x
  {
    f32x4 acc[4][4] = {};
    for (int k = 0; k < 8; ++k){
      int d0 = k*32 + g*8;
      s16x8 bv[4];
      #pragma unroll
      for (int pt = 0; pt < 4; ++pt){
        int p = pt*16 + lr;
        bv[pt] = *(const s16x8*)&As[p*256 + (d0 ^ ((p & 7) << 3))];
      }
      #pragma unroll
      for (int i = 0; i < 4; ++i){
        int o0 = (w*4 + i)*16;
        s16x8 a = *(const s16x8*)(Qb + (size_t)(o0 + lr)*256 + d0);
        #pragma unroll
        for (int pt = 0; pt < 4; ++pt)
          acc[i][pt] = mfma16(a, bv[pt], acc[i][pt]);
      }
    }
    #pragma unroll
    for (int i = 0; i < 4; ++i){
      int o0 = (w*4 + i)*16;
      f32x4 gg = *(const f32x4*)(gvec + b*512 + o0 + 4*g);
      #pragma unroll
      for (int pt = 0; pt < 4; ++pt){
        #pragma unroll
        for (int r = 0; r < 4; ++r){
          size_t idx = (size_t)(b*CC + o0 + 4*g + r)*HWP + p0 + pt*16 + lr;
          out[idx] = fmaf(acc[i][pt][r], gg[r], xr[(i*4 + pt)*4 + r]);
        }
      }
    }
  }
}

extern "C" void kernel_launch(void* const* d_in, const int* in_sizes, int n_in,
                              void* d_out, int out_size, void* d_ws, size_t ws_size,
                              hipStream_t stream) {
  const float* x    = (const float*)d_in[0];
  const float* wg   = (const float*)d_in[1];
  const float* Wg   = (const float*)d_in[2];
  const float* gamg = (const float*)d_in[3];
  const float* betg = (const float*)d_in[4];
  const float* Wc   = (const float*)d_in[5];
  const float* gamc = (const float*)d_in[6];
  const float* betc = (const float*)d_in[7];
  float* out = (float*)d_out;

  int kspl = 1;
  {
    size_t base = (size_t)1320448 + 524288 + 393216;
    if (ws_size >= (base + (size_t)2*16*262144) * 4) kspl = 2;
  }

  float* ws = (float*)d_ws;
  float* G     = ws + 0;
  float* U     = ws + 65536;
  float* Q     = ws + 131072;
  float* Qst   = ws + 262144;
  float* S     = ws + 393216;
  float* xbar  = ws + 655360;
  float* bgf   = ws + 918016;
  float* bcf   = ws + 1180672;
  float* gvec  = ws + 1181184;
  float* Spart = ws + 1320448;
  float* gpart = Spart + (size_t)kspl*16*262144;
  u16*   ub    = (u16*)(gpart + 524288);
  u16* Qb   = ub;
  u16* Qstb = ub + 131072;
  u16* Wgb  = ub + 262144;
  u16* Wcb  = ub + 524288;

  hipMemsetAsync(xbar, 0, 512*sizeof(float), stream);
  k_gram<<<dim3(10,16,kspl), 512, 0, stream>>>(x, Spart, xbar, kspl);
  k_sredG<<<1280, 256, 0, stream>>>(Spart, S, 16*kspl, wg, G);
  for (int kb = 0; kb < 8; ++kb){
    int nt = 256 - kb*32 - 32;
    int T = (nt + 63) >> 6;
    int nblk = (nt > 0) ? T*(T+1)/2 : 1;
    k_cholStep<<<nblk, 256, 0, stream>>>(G, U, kb);
  }
  k_qsolve<<<8, 256, 0, stream>>>(U, wg, Q, Qst, Qb, Qstb);
  k_fold<<<1024, 256, 0, stream>>>(Wg, Wc, gamg, betg, gamc, betc, S, xbar, bgf, bcf, Wgb, Wcb);
  k_gconv<<<dim3(64,16), 512, 0, stream>>>(x, Wgb, bgf, gpart);
  k_gvec<<<16, 256, 0, stream>>>(gpart, Q, Qst, gvec);
  k_fused<<<dim3(64,16), 512, 0, stream>>>(x, Wcb, bcf, Qstb, Qb, gvec, out);
}